// Round 15
// baseline (393.733 us; speedup 1.0000x reference)
//
#include <hip/hip_runtime.h>
#include <float.h>
#include <math.h>

#define D 256
#define NROWS 65536
#define RPB_S 32              // rows per score block (1 row-tile, 2 waves split cols)
#define NBLK_S (NROWS / RPB_S)   // 2048
#define RPB_E 128             // rows per epi block
#define NBLK_E (NROWS / RPB_E)   // 512
#define NT 30
#define EPS_CAND 0.02f
#define CAP 3
#define WSFRAG 1024
#define WSKF   246784         // kfin ushort[2048 blocks][4 dicts][32 rows] = 512KB
#define WSDT   377856         // optional fp32 dicT[960][256]
#define ASTRIDE 520

typedef __attribute__((ext_vector_type(8)))  short short8v;
typedef __attribute__((ext_vector_type(16))) float f32x16;
typedef __attribute__((ext_vector_type(4)))  float float4v;
typedef __attribute__((ext_vector_type(4)))  uint  uint4v;

__device__ __forceinline__ ushort f2bf(float v) {
    uint u = __float_as_uint(v);
    u += 0x7fffu + ((u >> 16) & 1u);
    return (ushort)(u >> 16);
}
__device__ __forceinline__ float bf2f(ushort u) { return __uint_as_float(((uint)u) << 16); }

__device__ __forceinline__ int fidx(int ct, int c, int s, int half, int j, int p) {
    return ((ct * 16 + s) * 2 + p) * 512 + (c + 32 * half) * 8 + j;   // ws frag layout
}
__device__ __forceinline__ float dget(const ushort* fr, int pc, int d) {
    int b = fidx(pc >> 5, pc & 31, d >> 4, (d >> 3) & 1, d & 7, 0);
    return bf2f(fr[b]) + bf2f(fr[b + 512]);
}
__device__ __forceinline__ void dic_sel(int pc, const float* dc0, const float* dc1,
                                        const float* dc2, const float* dc3,
                                        const float*& dic, int& K, int& kk) {
    if      (pc < 64)  { dic = dc0; K = 64;  kk = pc;       }
    else if (pc < 192) { dic = dc1; K = 128; kk = pc - 64;  }
    else if (pc < 448) { dic = dc2; K = 256; kk = pc - 192; }
    else               { dic = dc3; K = 512; kk = pc - 448; }
}

__global__ void vq_prep(const float* __restrict__ av,
                        const float* __restrict__ dc0, const float* __restrict__ dc1,
                        const float* __restrict__ dc2, const float* __restrict__ dc3,
                        float* __restrict__ ws, float* __restrict__ dT)
{
    int t = blockIdx.x * 256 + threadIdx.x;
    ushort* fr = (ushort*)(ws + WSFRAG);
    if (t == 0) {
        double x0 = av[0], x1 = av[1], x2 = av[2], x3 = av[3];
        double m = fmax(fmax(x0, x1), fmax(x2, x3));
        double e0 = exp(x0 - m), e1 = exp(x1 - m), e2 = exp(x2 - m), e3 = exp(x3 - m);
        double inv = 1.0 / (e0 + e1 + e2 + e3);
        ws[0] = (float)(e0 * inv); ws[1] = (float)(e1 * inv);
        ws[2] = (float)(e2 * inv); ws[3] = (float)(e3 * inv);
        double* lacc = (double*)(ws + 968);
        lacc[0] = 0.0; lacc[1] = 0.0; lacc[2] = 0.0; lacc[3] = 0.0;
        double* dal = (double*)(ws + 976);
        dal[0] = e0 * inv; dal[1] = e1 * inv; dal[2] = e2 * inv; dal[3] = e3 * inv;
    }
    if (t < 960) {
        const float* dic; int K, kk;
        dic_sel(t, dc0, dc1, dc2, dc3, dic, K, kk);
        float s = 0.0f;
        if (dT != nullptr) {
            float* dr = dT + (size_t)t * D;
            for (int d = 0; d < D; ++d) {
                float v = dic[d * K + kk];
                s = __fadd_rn(s, __fmul_rn(v, v));
                dr[d] = v;
            }
        } else {
            for (int d = 0; d < D; ++d) {
                float v = dic[d * K + kk];
                s = __fadd_rn(s, __fmul_rn(v, v));
            }
        }
        ws[4 + t] = s;
    }
    if (t < 7680) {
        int pc = t >> 3;
        const float* dic; int K, kk;
        dic_sel(pc, dc0, dc1, dc2, dc3, dic, K, kk);
        int ct = pc >> 5, c = pc & 31;
        int kb = (t & 7) * 32;
        for (int k = kb; k < kb + 32; ++k) {
            float v = dic[k * K + kk];
            ushort hu = f2bf(v);
            ushort lu = f2bf(v - bf2f(hu));
            fr[fidx(ct, c, k >> 4, (k >> 3) & 1, k & 7, 0)] = hu;
            fr[fidx(ct, c, k >> 4, (k >> 3) & 1, k & 7, 1)] = lu;
        }
    }
}

__device__ __forceinline__ short8v load_B1(const ushort* bfr, int t, int s, int lane) {
    return *(const short8v*)&bfr[((t * 16 + s) * 2) * 512 + lane * 8];   // hi plane
}

// Score kernel: 2048 blocks x 128 thr. Wave 0 sweeps tiles [0,15), wave 1 [15,30).
// A (32 rows) in LDS, 1 ds_read_b128/kstep; B streamed from L2 with 4-buf dist-3 prefetch.
// NO barriers in the GEMM loops -> latency hidden by 4 waves/SIMD TLP.
__global__ void __launch_bounds__(128, 4) vq_score(
    const float* __restrict__ x,
    const float* __restrict__ dc0, const float* __restrict__ dc1,
    const float* __restrict__ dc2, const float* __restrict__ dc3,
    float* __restrict__ ws, const float* __restrict__ dT, ushort* __restrict__ wkf)
{
    __shared__ __align__(16) ushort afrag[16 * ASTRIDE];   // 16,640 B
    __shared__ float thrL[4][32];
    __shared__ float f2row[32];
    __shared__ int   cnt[4][32];
    __shared__ int   cand[4][32][CAP];     // pass2; overlaid by slotmin float[5][32] in pass1
    __shared__ ushort rep_list[128];
    __shared__ int   rep_cnt;

    float* slotminp = (float*)&cand[0][0][0];   // 160 floats <= 384 ints, disjoint lifetime

    const int tid  = threadIdx.x;
    const int lane = tid & 63;
    const int wv   = __builtin_amdgcn_readfirstlane(tid >> 6);   // 0 or 1
    const int lcol = lane & 31, half = lane >> 5;
    const size_t rowbase = (size_t)blockIdx.x * RPB_S;

    if (tid == 0) rep_cnt = 0;
    (&cnt[0][0])[tid] = 0;   // 128 ints, 128 threads

    // ---- A stage: 32 rows -> bf16 hi fragments in LDS ----
    const float4v* x4 = (const float4v*)(x + rowbase * D);
    for (int it = 0; it < 8; ++it) {
        int f = it * 128 + tid;                 // 1024 b128-units
        int row = f >> 5, sh = f & 31, s = sh >> 1, hf = sh & 1;
        float4v va = __builtin_nontemporal_load(&x4[row * 64 + s * 4 + hf * 2]);
        float4v vb = __builtin_nontemporal_load(&x4[row * 64 + s * 4 + hf * 2 + 1]);
        ushort h[8];
#pragma unroll
        for (int i = 0; i < 4; ++i) { h[i] = f2bf(va[i]); h[4 + i] = f2bf(vb[i]); }
        int bu = s * ASTRIDE + (row + 32 * hf) * 8;
        uint4v Hv = { (uint)h[0] | ((uint)h[1] << 16), (uint)h[2] | ((uint)h[3] << 16),
                      (uint)h[4] | ((uint)h[5] << 16), (uint)h[6] | ((uint)h[7] << 16) };
        *(uint4v*)&afrag[bu] = Hv;
    }

    // f2 per row from exact global x (fp64 -> fp32)
    if (tid < 32) {
        const float* xr = x + (rowbase + tid) * D;
        double s = 0.0;
        for (int d0 = 0; d0 < D; d0 += 4) {
            float4v v = *(const float4v*)&xr[d0];
#pragma unroll
            for (int j = 0; j < 4; ++j) s = fma((double)v[j], (double)v[j], s);
        }
        f2row[tid] = (float)s;
    }
    __syncthreads();

    const ushort* bfr = (const ushort*)(ws + WSFRAG);
    const float*  c2g = ws + 4;
    const int ts = wv ? 15 : 0;
    const int te = wv ? 30 : 15;

    auto ldsA = [&](int s) -> short8v {
        return *(const short8v*)&afrag[s * ASTRIDE + lane * 8];
    };

    // barrier-free GEMM sweep over this wave's tiles; pass1/pass2 bitwise identical
    auto run_pass = [&](auto&& emit) {
        short8v A[2], B[4];
        A[0] = ldsA(0);
        B[0] = load_B1(bfr, ts, 0, lane);
        B[1] = load_B1(bfr, ts, 1, lane);
        B[2] = load_B1(bfr, ts, 2, lane);
        for (int kt = ts; kt < te; ++kt) {
            f32x16 acc = (f32x16)(0.0f);
#pragma unroll
            for (int s = 0; s < 16; ++s) {
                const int pt = kt + ((s + 3) >> 4);          // prefetch dist 3 <= bufs-1
                if (pt < te) B[(s + 3) & 3] = load_B1(bfr, pt, (s + 3) & 15, lane);
                A[(s + 1) & 1] = ldsA((s + 1) & 15);
                acc = __builtin_amdgcn_mfma_f32_32x32x16_bf16(A[s & 1], B[s & 3], acc, 0, 0, 0);
            }
            emit(kt, acc);
        }
    };

    // ---- pass 1: per-(dict,row) min -> slots (d3 split across waves) ----
    {
        float rv[16];
#pragma unroll
        for (int r = 0; r < 16; ++r) rv[r] = FLT_MAX;
        run_pass([&](int kt, const f32x16& a) {
            const float c2t = c2g[kt * 32 + lcol];
#pragma unroll
            for (int r = 0; r < 16; ++r)
                rv[r] = fminf(rv[r], fmaf(-2.0f, a[r], c2t));
            int slot = -1;   // wave-uniform
            if (wv == 0) {
                if      (kt == 1)  slot = 0;   // d0 end
                else if (kt == 5)  slot = 1;   // d1 end
                else if (kt == 13) slot = 2;   // d2 end
                else if (kt == 14) slot = 3;   // d3 partial (wave0)
            } else if (kt == 29)   slot = 4;   // d3 partial (wave1)
            if (slot >= 0) {
#pragma unroll
                for (int r = 0; r < 16; ++r) {
                    float v = rv[r];
#pragma unroll
                    for (int off = 1; off <= 16; off <<= 1) v = fminf(v, __shfl_xor(v, off));
                    if (lcol == r)
                        slotminp[slot * 32 + (r & 3) + 8 * (r >> 2) + 4 * half] = v;
                    rv[r] = FLT_MAX;
                }
            }
        });
    }
    __syncthreads();

    // ---- threshold combine: d0..d2 direct, d3 = min(slot3, slot4) ----
    {
        int i = tid >> 5, r = tid & 31;      // 128 threads = 4 dicts x 32 rows
        float m1 = (i < 3) ? slotminp[i * 32 + r]
                           : fminf(slotminp[96 + r], slotminp[128 + r]);
        thrL[i][r] = m1 + EPS_CAND;
    }
    __syncthreads();

    // ---- pass 2: recompute (bitwise same), collect candidates ----
    run_pass([&](int kt, const f32x16& a) {
        const float c2t = c2g[kt * 32 + lcol];
        const int dct = (kt < 2) ? 0 : (kt < 6) ? 1 : (kt < 14) ? 2 : 3;
#pragma unroll
        for (int r = 0; r < 16; ++r) {
            float sc = fmaf(-2.0f, a[r], c2t);
            const int row = (r & 3) + 8 * (r >> 2) + 4 * half;
            if (sc < thrL[dct][row]) {
                int pos = atomicAdd(&cnt[dct][row], 1);
                if (pos < CAP) cand[dct][row][pos] = kt * 32 + lcol;
            }
        }
    });
    __syncthreads();

    // ---- final select: np-mimic among candidates; one (dict,row) per thread ----
    ushort* kf = wkf + (size_t)blockIdx.x * 128;
    {
        const int i = tid >> 5, r = tid & 31;
        const int n = cnt[i][r];
        if (n > CAP) {
            int q = atomicAdd(&rep_cnt, 1);
            rep_list[q] = (ushort)tid;
        } else {
            const float f2 = f2row[r];
            const float* xrow = x + (rowbase + r) * D;
            float best = FLT_MAX; int bi = 0x7fffffff;
            for (int j = 0; j < n; ++j) {
                const int pc = cand[i][r][j];
                double smd = 0.0;
                if (dT != nullptr) {
                    const float* br = dT + (size_t)pc * D;
                    for (int d0 = 0; d0 < D; d0 += 4) {
                        float4v xa = *(const float4v*)&xrow[d0];
                        float4v bb = *(const float4v*)&br[d0];
#pragma unroll
                        for (int j2 = 0; j2 < 4; ++j2)
                            smd = fma((double)xa[j2], (double)bb[j2], smd);
                    }
                } else {
                    for (int d0 = 0; d0 < D; d0 += 8) {
                        float4v xa = *(const float4v*)&xrow[d0];
                        float4v xb = *(const float4v*)&xrow[d0 + 4];
                        int bb = fidx(pc >> 5, pc & 31, d0 >> 4, (d0 >> 3) & 1, 0, 0);
                        short8v bh = *(const short8v*)&bfr[bb];
                        short8v bl = *(const short8v*)&bfr[bb + 512];
#pragma unroll
                        for (int j2 = 0; j2 < 4; ++j2) {
                            double bv0 = (double)(bf2f((ushort)bh[j2]) + bf2f((ushort)bl[j2]));
                            double bv1 = (double)(bf2f((ushort)bh[4 + j2]) + bf2f((ushort)bl[4 + j2]));
                            smd = fma((double)xa[j2], bv0, smd);
                            smd = fma((double)xb[j2], bv1, smd);
                        }
                    }
                }
                float sim  = (float)smd;
                float dist = __fsub_rn(__fadd_rn(f2, c2g[pc]), __fmul_rn(2.0f, sim));
                if (dist < best || (dist == best && pc < bi)) { best = dist; bi = pc; }
            }
            kf[i * 32 + r] = (ushort)bi;
        }
    }
    __syncthreads();

    // ---- rare fallback: full np-mimic scan (one wave per overflowed pair) ----
    for (int t = wv; t < rep_cnt; t += 2) {
        int e = rep_list[t];
        int i = e >> 5, r = e & 31;
        const float* dic; int K, base;
        if      (i == 0) { dic = dc0; K = 64;  base = 0;   }
        else if (i == 1) { dic = dc1; K = 128; base = 64;  }
        else if (i == 2) { dic = dc2; K = 256; base = 192; }
        else             { dic = dc3; K = 512; base = 448; }
        const float* xrow = x + (rowbase + r) * D;
        const float f2 = f2row[r];
        float bestv = FLT_MAX; int besti = 0x7fffffff;
        for (int c = lane; c < K; c += 64) {
            float  cn  = 0.0f;
            double smd = 0.0;
            for (int d = 0; d < D; ++d) {
                float bv = dic[d * K + c];
                cn  = __fadd_rn(cn, __fmul_rn(bv, bv));
                smd = fma((double)xrow[d], (double)bv, smd);
            }
            float sim  = (float)smd;
            float dist = __fsub_rn(__fadd_rn(f2, cn), __fmul_rn(2.0f, sim));
            if (dist < bestv) { bestv = dist; besti = c; }
        }
#pragma unroll
        for (int off = 32; off; off >>= 1) {
            float ov = __shfl_xor(bestv, off);
            int   oi = __shfl_xor(besti, off);
            if (ov < bestv || (ov == bestv && oi < besti)) { bestv = ov; besti = oi; }
        }
        if (lane == 0) kf[i * 32 + r] = (ushort)(base + besti);
    }
}

__global__ void vq_epi(const float* __restrict__ x, float* __restrict__ ws,
                       const float* __restrict__ dT, const ushort* __restrict__ wkf,
                       float* __restrict__ out)
{
    __shared__ double lred[4][4];
    __shared__ int kf[512];

    const int tid  = threadIdx.x;
    const int lane = tid & 63;
    const int wv   = __builtin_amdgcn_readfirstlane(tid >> 6);
    const size_t rowbase = (size_t)blockIdx.x * RPB_E;
    const ushort* bfr = (const ushort*)(ws + WSFRAG);

    // kf[i*128 + r] for r in [0,128): score block = blockIdx.x*4 + (r>>5)
#pragma unroll
    for (int p0 = 0; p0 < 512; p0 += 256) {
        int p = p0 + tid;
        int i = p >> 7, r = p & 127;
        kf[p] = wkf[(size_t)(blockIdx.x * 4 + (r >> 5)) * 128 + i * 32 + (r & 31)];
    }
    __syncthreads();

    const float a0 = ws[0], a1 = ws[1], a2 = ws[2], a3 = ws[3];
    double l0 = 0.0, l1 = 0.0, l2 = 0.0, l3 = 0.0;
#pragma unroll 4
    for (int r = 0; r < RPB_E; ++r) {
        const float xv = __builtin_nontemporal_load(&x[(rowbase + r) * D + tid]);
        const int i0 = kf[r], i1 = kf[128 + r], i2 = kf[256 + r], i3 = kf[384 + r];
        float q0, q1, q2, q3;
        if (dT != nullptr) {
            q0 = dT[(size_t)i0 * D + tid];
            q1 = dT[(size_t)i1 * D + tid];
            q2 = dT[(size_t)i2 * D + tid];
            q3 = dT[(size_t)i3 * D + tid];
        } else {
            q0 = dget(bfr, i0, tid);
            q1 = dget(bfr, i1, tid);
            q2 = dget(bfr, i2, tid);
            q3 = dget(bfr, i3, tid);
        }
        float wq = __fadd_rn(__fadd_rn(__fadd_rn(__fmul_rn(a0, q0), __fmul_rn(a1, q1)),
                                       __fmul_rn(a2, q2)), __fmul_rn(a3, q3));
        __builtin_nontemporal_store(__fadd_rn(xv, __fsub_rn(wq, xv)),
                                    &out[(rowbase + r) * D + tid]);
        const float e0 = xv - q0, e1 = xv - q1, e2 = xv - q2, e3 = xv - q3;
        l0 = fma((double)e0, (double)e0, l0);
        l1 = fma((double)e1, (double)e1, l1);
        l2 = fma((double)e2, (double)e2, l2);
        l3 = fma((double)e3, (double)e3, l3);
    }
#pragma unroll
    for (int off = 32; off; off >>= 1) {
        l0 += __shfl_down(l0, off); l1 += __shfl_down(l1, off);
        l2 += __shfl_down(l2, off); l3 += __shfl_down(l3, off);
    }
    if (lane == 0) { lred[wv][0] = l0; lred[wv][1] = l1; lred[wv][2] = l2; lred[wv][3] = l3; }
    __syncthreads();
    if (tid == 0) {
        double* lacc = (double*)(ws + 968);
#pragma unroll
        for (int i = 0; i < 4; ++i)
            atomicAdd(lacc + i, lred[0][i] + lred[1][i] + lred[2][i] + lred[3][i]);
    }
}

__global__ void vq_fin(const float* __restrict__ ws, float* __restrict__ out)
{
    if (threadIdx.x == 0) {
        const double* lacc = (const double*)(ws + 968);
        const double* dal  = (const double*)(ws + 976);
        double s = 0.0;
#pragma unroll
        for (int i = 0; i < 4; ++i) s += (lacc[i] * (1.0 / 16777216.0)) * dal[i];
        out[16777216] = (float)(s + 0.25 * s);
    }
}

extern "C" void kernel_launch(void* const* d_in, const int* in_sizes, int n_in,
                              void* d_out, int out_size, void* d_ws, size_t ws_size,
                              hipStream_t stream)
{
    const float* x   = (const float*)d_in[0];
    const float* av  = (const float*)d_in[1];
    const float* dc0 = (const float*)d_in[2];
    const float* dc1 = (const float*)d_in[3];
    const float* dc2 = (const float*)d_in[4];
    const float* dc3 = (const float*)d_in[5];
    float* out = (float*)d_out;
    float* ws  = (float*)d_ws;

    ushort* wkf = (ushort*)(ws + WSKF);
    const bool haveDT = ws_size >= (size_t)(WSDT + 960 * 256) * sizeof(float);
    float* dT = haveDT ? (ws + WSDT) : nullptr;

    hipLaunchKernelGGL(vq_prep, dim3(30), dim3(256), 0, stream, av, dc0, dc1, dc2, dc3, ws, dT);
    hipLaunchKernelGGL(vq_score, dim3(NBLK_S), dim3(128), 0, stream,
                       x, dc0, dc1, dc2, dc3, ws, dT, wkf);
    hipLaunchKernelGGL(vq_epi, dim3(NBLK_E), dim3(256), 0, stream, x, ws, dT, wkf, out);
    hipLaunchKernelGGL(vq_fin, dim3(1), dim3(64), 0, stream, ws, out);
}